// Round 16
// baseline (991.984 us; speedup 1.0000x reference)
//
#include <hip/hip_runtime.h>

#define ETOT 524288
#define SGR  1024
#define NPG  64
#define EPG  512
#define NFD  32
#define EFD  16
#define HCD  64

typedef float f2v __attribute__((ext_vector_type(2)));

__device__ __forceinline__ float elu_(float x){ return x>0.f ? x : (__expf(x)-1.f); }
__device__ __forceinline__ float sig_(float x){ return 1.f/(1.f+__expf(-x)); }
__device__ __forceinline__ float tanhf_(float x){ float e=__expf(2.f*x); return 1.f-2.f/(e+1.f); }
__device__ __forceinline__ float lrelu_(float x){ return x>0.f ? x : 0.2f*x; }

template<int C>
__device__ __forceinline__ float dppf(float v){
  return __int_as_float(__builtin_amdgcn_update_dpp(0, __float_as_int(v), C, 0xF, 0xF, true));
}

// ===== GAT: r9-exact (known 282 us combined; r15's f2v/scatter variant regressed) =====
__device__ void build_csr_la(int tid, int g, const int* ei, const float* ea,
                             int* s_edge, int* s_entry, int* s_off, int* s_deg,
                             int* s_cnt, float* s_la)
{
  const int base = g*NPG;
  const int* srcp = ei + (size_t)g*EPG;
  const int* dstp = ei + (size_t)ETOT + (size_t)g*EPG;
  s_edge[tid] = (srcp[tid]-base) | ((dstp[tid]-base)<<6);
  __syncthreads();
  { const int d=tid>>3, s=tid&7, b0=s*64;
    int c=0;
    #pragma unroll 8
    for(int i=0;i<64;i++) c += (((s_edge[b0+i]>>6)&63)==d);
    s_cnt[(d<<3)|s]=c; }
  __syncthreads();
  if(tid<64){ int a=0;
    #pragma unroll
    for(int s=0;s<8;s++) a+=s_cnt[(tid<<3)|s];
    s_deg[tid]=a; }
  __syncthreads();
  if(tid==0){ int a=0;
    for(int i=0;i<64;i++){ s_off[i]=a; a+=s_deg[i]; }
    s_off[64]=a; }
  __syncthreads();
  { const int d=tid>>3, s=tid&7, b0=s*64;
    int pos=s_off[d];
    for(int s2=0;s2<s;s2++) pos += s_cnt[(d<<3)|s2];
    for(int i=0;i<64;i++){ int en=s_edge[b0+i];
      if(((en>>6)&63)==d) s_entry[pos++] = (en&63) | (d<<6) | ((b0+i)<<12); } }
  __syncthreads();
  if(tid<256){ int n=tid>>2, f0=(tid&3)*4;
    float a0=0,a1=0,a2=0,a3=0;
    const int b=s_off[n], en=s_off[n+1];
    for(int p=b;p<en;p++){ int eid=s_entry[p]>>12;
      const float4 v = *(const float4*)(ea + ((size_t)g*EPG+(size_t)eid)*EFD + f0);
      a0+=v.x; a1+=v.y; a2+=v.z; a3+=v.w; }
    float inv = 1.f/fmaxf((float)(en-b),1.f);
    float4 r; r.x=a0*inv; r.y=a1*inv; r.z=a2*inv; r.w=a3*inv;
    *(float4*)(s_la + n*EFD + f0) = r; }
  __syncthreads();
}

__device__ void scores_softmax(int tid, int g, const float* ea,
   const int* s_entry, const int* s_off, const float* s_la,
   const float* s_We, const float* s_att, const float* s_xl, const float* s_xr,
   float* s_sc)
{
  for(int p=tid;p<576;p+=512){
    int src,dst; float eav[16];
    if(p<EPG){
      int en=s_entry[p]; src=en&63; dst=(en>>6)&63; int eid=en>>12;
      const float* epp = ea + ((size_t)g*EPG + (size_t)eid)*EFD;
      float4 v0=*(const float4*)(epp),   v1=*(const float4*)(epp+4);
      float4 v2=*(const float4*)(epp+8), v3=*(const float4*)(epp+12);
      eav[0]=v0.x;eav[1]=v0.y;eav[2]=v0.z;eav[3]=v0.w;
      eav[4]=v1.x;eav[5]=v1.y;eav[6]=v1.z;eav[7]=v1.w;
      eav[8]=v2.x;eav[9]=v2.y;eav[10]=v2.z;eav[11]=v2.w;
      eav[12]=v3.x;eav[13]=v3.y;eav[14]=v3.z;eav[15]=v3.w;
    } else {
      int n=p-EPG; src=n; dst=n;
      const float* epp = s_la + n*EFD;
      float4 v0=*(const float4*)(epp),   v1=*(const float4*)(epp+4);
      float4 v2=*(const float4*)(epp+8), v3=*(const float4*)(epp+12);
      eav[0]=v0.x;eav[1]=v0.y;eav[2]=v0.z;eav[3]=v0.w;
      eav[4]=v1.x;eav[5]=v1.y;eav[6]=v1.z;eav[7]=v1.w;
      eav[8]=v2.x;eav[9]=v2.y;eav[10]=v2.z;eav[11]=v2.w;
      eav[12]=v3.x;eav[13]=v3.y;eav[14]=v3.z;eav[15]=v3.w;
    }
    float score=0.f;
    #pragma unroll 4
    for(int cq=0;cq<16;cq++){
      float e0=0.f,e1=0.f,e2=0.f,e3=0.f;
      #pragma unroll
      for(int f=0;f<16;f++){
        const float4 wv=*(const float4*)(s_We + f*64 + cq*4);
        e0+=eav[f]*wv.x; e1+=eav[f]*wv.y; e2+=eav[f]*wv.z; e3+=eav[f]*wv.w;
      }
      const float4 xlv=*(const float4*)(s_xl + src*64 + ((cq^(src&15))<<2));
      const float4 xrv=*(const float4*)(s_xr + dst*64 + ((cq^(dst&15))<<2));
      const float4 av =*(const float4*)(s_att + cq*4);
      float m0=lrelu_(xlv.x+xrv.x+e0), m1=lrelu_(xlv.y+xrv.y+e1);
      float m2=lrelu_(xlv.z+xrv.z+e2), m3=lrelu_(xlv.w+xrv.w+e3);
      score += m0*av.x+m1*av.y+m2*av.z+m3*av.w;
    }
    s_sc[p]=score;
  }
  __syncthreads();
  { const int d=tid>>3, s=tid&7;
    const int b=s_off[d], e=s_off[d+1];
    float mx=-1e30f;
    for(int p=b+s;p<e;p+=8) mx=fmaxf(mx,s_sc[p]);
    if(s==0) mx=fmaxf(mx,s_sc[EPG+d]);
    mx=fmaxf(mx,dppf<0xB1>(mx));
    mx=fmaxf(mx,dppf<0x4E>(mx));
    mx=fmaxf(mx,dppf<0x141>(mx));
    float den=0.f;
    for(int p=b+s;p<e;p+=8){ float w=__expf(s_sc[p]-mx); s_sc[p]=w; den+=w; }
    float selfv=0.f;
    if(s==0){ selfv=__expf(s_sc[EPG+d]-mx); den+=selfv; }
    den+=dppf<0xB1>(den);
    den+=dppf<0x4E>(den);
    den+=dppf<0x141>(den);
    const float inv=1.f/(den+1e-16f);
    for(int p=b+s;p<e;p+=8) s_sc[p]*=inv;
    if(s==0) s_sc[EPG+d]=selfv*inv;
  }
  __syncthreads();
}

__global__ __launch_bounds__(512,4) void gat1_k(
    const float* __restrict__ x, const int* __restrict__ ei,
    const float* __restrict__ ea, const float* __restrict__ Wl,
    const float* __restrict__ bl, const float* __restrict__ Wr,
    const float* __restrict__ br, const float* __restrict__ We,
    const float* __restrict__ att, const float* __restrict__ bias,
    float* __restrict__ h1)
{
  const int g = blockIdx.x, tid = threadIdx.x;
  const int base = g*NPG;

  __shared__ __align__(16) float s_x[NPG*36];
  __shared__ __align__(16) float s_xl[NPG*64];
  __shared__ __align__(16) float s_xr[NPG*64];
  __shared__ __align__(16) float s_W[2*32*64];
  __shared__ __align__(16) float s_We[16*64];
  __shared__ __align__(16) float s_att[64];
  __shared__ __align__(16) float s_la[NPG*EFD];
  __shared__ float s_sc[576];
  __shared__ int   s_edge[EPG];
  __shared__ int   s_entry[EPG];
  __shared__ int   s_cnt[512];
  __shared__ int   s_off[65];
  __shared__ int   s_deg[64];

  { int n=tid>>3, kq=tid&7;
    float4 v = *(const float4*)(x + (size_t)(base+n)*NFD + kq*4);
    *(float4*)(s_x + n*36 + kq*4) = v; }

  build_csr_la(tid, g, ei, ea, s_edge, s_entry, s_off, s_deg, s_cnt, s_la);

  for(int h=0;h<3;h++){
    { int k=tid>>4, c0=(tid&15)*4;
      *(float4*)(s_W + k*64 + c0)        = *(const float4*)(Wl + (size_t)k*192 + h*64 + c0);
      *(float4*)(s_W + 2048 + k*64 + c0) = *(const float4*)(Wr + (size_t)k*192 + h*64 + c0); }
    if(tid<256){ int f=tid>>4, c0=(tid&15)*4;
      *(float4*)(s_We + f*64 + c0) = *(const float4*)(We + (size_t)f*192 + h*64 + c0); }
    if(tid<16) *(float4*)(s_att + tid*4) = *(const float4*)(att + h*64 + tid*4);
    __syncthreads();

    { const int cg=tid&15, ng=tid>>4, n0=ng*2, c0=cg*4;
      const float4 blv=*(const float4*)(bl + h*64 + c0);
      const float4 brv=*(const float4*)(br + h*64 + c0);
      float accl[2][4]={{blv.x,blv.y,blv.z,blv.w},{blv.x,blv.y,blv.z,blv.w}};
      float accr[2][4]={{brv.x,brv.y,brv.z,brv.w},{brv.x,brv.y,brv.z,brv.w}};
      #pragma unroll
      for(int kq=0;kq<8;kq++){
        float xs0[4], xs1[4];
        { float4 v=*(const float4*)(s_x + n0*36 + kq*4);     xs0[0]=v.x;xs0[1]=v.y;xs0[2]=v.z;xs0[3]=v.w; }
        { float4 v=*(const float4*)(s_x + (n0+1)*36 + kq*4); xs1[0]=v.x;xs1[1]=v.y;xs1[2]=v.z;xs1[3]=v.w; }
        #pragma unroll
        for(int f=0;f<4;f++){
          const float4 wl=*(const float4*)(s_W + (kq*4+f)*64 + c0);
          const float4 wr=*(const float4*)(s_W + 2048 + (kq*4+f)*64 + c0);
          accl[0][0]+=xs0[f]*wl.x; accl[0][1]+=xs0[f]*wl.y; accl[0][2]+=xs0[f]*wl.z; accl[0][3]+=xs0[f]*wl.w;
          accl[1][0]+=xs1[f]*wl.x; accl[1][1]+=xs1[f]*wl.y; accl[1][2]+=xs1[f]*wl.z; accl[1][3]+=xs1[f]*wl.w;
          accr[0][0]+=xs0[f]*wr.x; accr[0][1]+=xs0[f]*wr.y; accr[0][2]+=xs0[f]*wr.z; accr[0][3]+=xs0[f]*wr.w;
          accr[1][0]+=xs1[f]*wr.x; accr[1][1]+=xs1[f]*wr.y; accr[1][2]+=xs1[f]*wr.z; accr[1][3]+=xs1[f]*wr.w;
        }
      }
      #pragma unroll
      for(int i=0;i<2;i++){
        const int n=n0+i, sq=((cg^(n&15))<<2);
        float4 vl; vl.x=accl[i][0]; vl.y=accl[i][1]; vl.z=accl[i][2]; vl.w=accl[i][3];
        float4 vr; vr.x=accr[i][0]; vr.y=accr[i][1]; vr.z=accr[i][2]; vr.w=accr[i][3];
        *(float4*)(s_xl + n*64 + sq)=vl;
        *(float4*)(s_xr + n*64 + sq)=vr;
      }
    }
    __syncthreads();

    scores_softmax(tid, g, ea, s_entry, s_off, s_la, s_We, s_att, s_xl, s_xr, s_sc);

    { const int n=tid>>3, c0a=(tid&7)*8;
      float acc[8]={0.f,0.f,0.f,0.f,0.f,0.f,0.f,0.f};
      const int b=s_off[n], e=s_off[n+1];
      for(int p=b;p<e;p++){
        const int en=s_entry[p], src=en&63;
        const float a=s_sc[p];
        #pragma unroll
        for(int qq=0;qq<2;qq++){
          const int cq=(c0a>>2)+qq;
          const float4 xv=*(const float4*)(s_xl + src*64 + ((cq^(src&15))<<2));
          acc[qq*4+0]+=a*xv.x; acc[qq*4+1]+=a*xv.y; acc[qq*4+2]+=a*xv.z; acc[qq*4+3]+=a*xv.w;
        }
      }
      { const float a=s_sc[EPG+n];
        #pragma unroll
        for(int qq=0;qq<2;qq++){
          const int cq=(c0a>>2)+qq;
          const float4 xv=*(const float4*)(s_xl + n*64 + ((cq^(n&15))<<2));
          acc[qq*4+0]+=a*xv.x; acc[qq*4+1]+=a*xv.y; acc[qq*4+2]+=a*xv.z; acc[qq*4+3]+=a*xv.w;
        } }
      float* op = h1 + (size_t)(base+n)*192 + h*64 + c0a;
      #pragma unroll
      for(int qq=0;qq<2;qq++){
        const float4 bv=*(const float4*)(bias + h*64 + c0a + qq*4);
        float4 r; r.x=elu_(acc[qq*4+0]+bv.x); r.y=elu_(acc[qq*4+1]+bv.y);
                  r.z=elu_(acc[qq*4+2]+bv.z); r.w=elu_(acc[qq*4+3]+bv.w);
        *(float4*)(op + qq*4)=r;
      }
    }
    __syncthreads();
  }
}

__global__ __launch_bounds__(512,4) void gat2_k(
    const float* __restrict__ h1, const int* __restrict__ ei,
    const float* __restrict__ ea, const float* __restrict__ Wl,
    const float* __restrict__ bl, const float* __restrict__ Wr,
    const float* __restrict__ br, const float* __restrict__ We,
    const float* __restrict__ att, const float* __restrict__ bias,
    const float* __restrict__ Wih, const float* __restrict__ bih,
    const float* __restrict__ bhh, float* __restrict__ xproj)
{
  const int g = blockIdx.x, tid = threadIdx.x;
  const int base = g*NPG;

  __shared__ __align__(16) float s_hx[NPG*36];
  __shared__ __align__(16) float s_xl[NPG*64];
  __shared__ __align__(16) float s_xr[NPG*64];
  __shared__ __align__(16) float s_W[2*32*64];
  __shared__ __align__(16) float s_We[16*64];
  __shared__ __align__(16) float s_att[64];
  __shared__ __align__(16) float s_la[NPG*EFD];
  __shared__ float s_sc[576];
  __shared__ float s_pool[64];
  __shared__ int   s_edge[EPG];
  __shared__ int   s_entry[EPG];
  __shared__ int   s_cnt[512];
  __shared__ int   s_off[65];
  __shared__ int   s_deg[64];
  float* s_out = s_W;

  build_csr_la(tid, g, ei, ea, s_edge, s_entry, s_off, s_deg, s_cnt, s_la);

  const int cg=tid&15, ng=tid>>4, n0=ng*2, gc0=cg*4;
  float accl[2][4], accr[2][4];
  { const float4 blv=*(const float4*)(bl + gc0);
    const float4 brv=*(const float4*)(br + gc0);
    #pragma unroll
    for(int i=0;i<2;i++){
      accl[i][0]=blv.x; accl[i][1]=blv.y; accl[i][2]=blv.z; accl[i][3]=blv.w;
      accr[i][0]=brv.x; accr[i][1]=brv.y; accr[i][2]=brv.z; accr[i][3]=brv.w; } }
  for(int kc=0;kc<6;kc++){
    { int n=tid>>3, kq=tid&7;
      *(float4*)(s_hx + n*36 + kq*4) = *(const float4*)(h1 + (size_t)(base+n)*192 + kc*32 + kq*4); }
    { int k=tid>>4, cc=(tid&15)*4;
      *(float4*)(s_W + k*64 + cc)        = *(const float4*)(Wl + (size_t)(kc*32+k)*64 + cc);
      *(float4*)(s_W + 2048 + k*64 + cc) = *(const float4*)(Wr + (size_t)(kc*32+k)*64 + cc); }
    __syncthreads();
    #pragma unroll
    for(int kq=0;kq<8;kq++){
      float xs0[4], xs1[4];
      { float4 v=*(const float4*)(s_hx + n0*36 + kq*4);     xs0[0]=v.x;xs0[1]=v.y;xs0[2]=v.z;xs0[3]=v.w; }
      { float4 v=*(const float4*)(s_hx + (n0+1)*36 + kq*4); xs1[0]=v.x;xs1[1]=v.y;xs1[2]=v.z;xs1[3]=v.w; }
      #pragma unroll
      for(int f=0;f<4;f++){
        const float4 wl=*(const float4*)(s_W + (kq*4+f)*64 + gc0);
        const float4 wr=*(const float4*)(s_W + 2048 + (kq*4+f)*64 + gc0);
        accl[0][0]+=xs0[f]*wl.x; accl[0][1]+=xs0[f]*wl.y; accl[0][2]+=xs0[f]*wl.z; accl[0][3]+=xs0[f]*wl.w;
        accl[1][0]+=xs1[f]*wl.x; accl[1][1]+=xs1[f]*wl.y; accl[1][2]+=xs1[f]*wl.z; accl[1][3]+=xs1[f]*wl.w;
        accr[0][0]+=xs0[f]*wr.x; accr[0][1]+=xs0[f]*wr.y; accr[0][2]+=xs0[f]*wr.z; accr[0][3]+=xs0[f]*wr.w;
        accr[1][0]+=xs1[f]*wr.x; accr[1][1]+=xs1[f]*wr.y; accr[1][2]+=xs1[f]*wr.z; accr[1][3]+=xs1[f]*wr.w;
      }
    }
    __syncthreads();
  }
  #pragma unroll
  for(int i=0;i<2;i++){
    const int n=n0+i, sq=((cg^(n&15))<<2);
    float4 vl; vl.x=accl[i][0]; vl.y=accl[i][1]; vl.z=accl[i][2]; vl.w=accl[i][3];
    float4 vr; vr.x=accr[i][0]; vr.y=accr[i][1]; vr.z=accr[i][2]; vr.w=accr[i][3];
    *(float4*)(s_xl + n*64 + sq)=vl;
    *(float4*)(s_xr + n*64 + sq)=vr;
  }
  if(tid<256){ int f=tid>>4, cc=(tid&15)*4;
    *(float4*)(s_We + f*64 + cc) = *(const float4*)(We + (size_t)f*64 + cc); }
  if(tid<16) *(float4*)(s_att + tid*4) = *(const float4*)(att + tid*4);
  __syncthreads();

  scores_softmax(tid, g, ea, s_entry, s_off, s_la, s_We, s_att, s_xl, s_xr, s_sc);

  { const int n=tid>>3, c0a=(tid&7)*8;
    float acc[8]={0.f,0.f,0.f,0.f,0.f,0.f,0.f,0.f};
    const int b=s_off[n], e=s_off[n+1];
    for(int p=b;p<e;p++){
      const int en=s_entry[p], src=en&63;
      const float a=s_sc[p];
      #pragma unroll
      for(int qq=0;qq<2;qq++){
        const int cq=(c0a>>2)+qq;
        const float4 xv=*(const float4*)(s_xl + src*64 + ((cq^(src&15))<<2));
        acc[qq*4+0]+=a*xv.x; acc[qq*4+1]+=a*xv.y; acc[qq*4+2]+=a*xv.z; acc[qq*4+3]+=a*xv.w;
      }
    }
    { const float a=s_sc[EPG+n];
      #pragma unroll
      for(int qq=0;qq<2;qq++){
        const int cq=(c0a>>2)+qq;
        const float4 xv=*(const float4*)(s_xl + n*64 + ((cq^(n&15))<<2));
        acc[qq*4+0]+=a*xv.x; acc[qq*4+1]+=a*xv.y; acc[qq*4+2]+=a*xv.z; acc[qq*4+3]+=a*xv.w;
      } }
    #pragma unroll
    for(int qq=0;qq<2;qq++){
      const float4 bv=*(const float4*)(bias + c0a + qq*4);
      float4 r; r.x=elu_(acc[qq*4+0]+bv.x); r.y=elu_(acc[qq*4+1]+bv.y);
                r.z=elu_(acc[qq*4+2]+bv.z); r.w=elu_(acc[qq*4+3]+bv.w);
      *(float4*)(s_out + n*64 + c0a + qq*4)=r;
    }
  }
  __syncthreads();
  if(tid<64){ float s=0.f;
    #pragma unroll 8
    for(int n2=0;n2<64;n2++) s += s_out[n2*64+tid];
    s_pool[tid]=s*(1.f/64.f); }
  __syncthreads();
  if(tid<256){
    float a=bih[tid]+bhh[tid];
    #pragma unroll
    for(int kq=0;kq<16;kq++){
      const float4 w=*(const float4*)(Wih + (size_t)tid*64 + kq*4);
      a += w.x*s_pool[kq*4+0] + w.y*s_pool[kq*4+1] + w.z*s_pool[kq*4+2] + w.w*s_pool[kq*4+3];
    }
    xproj[(size_t)g*256 + tid]=a;
  }
}

// ===== LSTM: SINGLE WAVE64, barrier-free. Lane l = node; ALL 256 weights (4 gates x 64)
// resident per lane as named f2v scalars (waves_per_eu(1,1) -> 512-VGPR budget; r7
// verified this attribute honors large allocations). No cross-lane reduce, no
// __syncthreads: wave-lockstep program order makes single-buffer s_h safe (all
// ds_reads of step t precede the ds_write of h_{t+1}; compiler inserts lgkmcnt).
#define WDECL32(m) \
  f2v w##m##_0,w##m##_1,w##m##_2,w##m##_3,w##m##_4,w##m##_5,w##m##_6,w##m##_7, \
      w##m##_8,w##m##_9,w##m##_10,w##m##_11,w##m##_12,w##m##_13,w##m##_14,w##m##_15, \
      w##m##_16,w##m##_17,w##m##_18,w##m##_19,w##m##_20,w##m##_21,w##m##_22,w##m##_23, \
      w##m##_24,w##m##_25,w##m##_26,w##m##_27,w##m##_28,w##m##_29,w##m##_30,w##m##_31; \
  { const float* wp_ = Whh + (size_t)((m)*64+l)*64; \
    float4 v_; \
    v_=*(const float4*)(wp_+ 0); w##m##_0 =(f2v){v_.x,v_.y}; w##m##_1 =(f2v){v_.z,v_.w}; \
    v_=*(const float4*)(wp_+ 4); w##m##_2 =(f2v){v_.x,v_.y}; w##m##_3 =(f2v){v_.z,v_.w}; \
    v_=*(const float4*)(wp_+ 8); w##m##_4 =(f2v){v_.x,v_.y}; w##m##_5 =(f2v){v_.z,v_.w}; \
    v_=*(const float4*)(wp_+12); w##m##_6 =(f2v){v_.x,v_.y}; w##m##_7 =(f2v){v_.z,v_.w}; \
    v_=*(const float4*)(wp_+16); w##m##_8 =(f2v){v_.x,v_.y}; w##m##_9 =(f2v){v_.z,v_.w}; \
    v_=*(const float4*)(wp_+20); w##m##_10=(f2v){v_.x,v_.y}; w##m##_11=(f2v){v_.z,v_.w}; \
    v_=*(const float4*)(wp_+24); w##m##_12=(f2v){v_.x,v_.y}; w##m##_13=(f2v){v_.z,v_.w}; \
    v_=*(const float4*)(wp_+28); w##m##_14=(f2v){v_.x,v_.y}; w##m##_15=(f2v){v_.z,v_.w}; \
    v_=*(const float4*)(wp_+32); w##m##_16=(f2v){v_.x,v_.y}; w##m##_17=(f2v){v_.z,v_.w}; \
    v_=*(const float4*)(wp_+36); w##m##_18=(f2v){v_.x,v_.y}; w##m##_19=(f2v){v_.z,v_.w}; \
    v_=*(const float4*)(wp_+40); w##m##_20=(f2v){v_.x,v_.y}; w##m##_21=(f2v){v_.z,v_.w}; \
    v_=*(const float4*)(wp_+44); w##m##_22=(f2v){v_.x,v_.y}; w##m##_23=(f2v){v_.z,v_.w}; \
    v_=*(const float4*)(wp_+48); w##m##_24=(f2v){v_.x,v_.y}; w##m##_25=(f2v){v_.z,v_.w}; \
    v_=*(const float4*)(wp_+52); w##m##_26=(f2v){v_.x,v_.y}; w##m##_27=(f2v){v_.z,v_.w}; \
    v_=*(const float4*)(wp_+56); w##m##_28=(f2v){v_.x,v_.y}; w##m##_29=(f2v){v_.z,v_.w}; \
    v_=*(const float4*)(wp_+60); w##m##_30=(f2v){v_.x,v_.y}; w##m##_31=(f2v){v_.z,v_.w}; } \
  asm volatile("" : "+v"(w##m##_0),"+v"(w##m##_1),"+v"(w##m##_2),"+v"(w##m##_3), \
                    "+v"(w##m##_4),"+v"(w##m##_5),"+v"(w##m##_6),"+v"(w##m##_7), \
                    "+v"(w##m##_8),"+v"(w##m##_9),"+v"(w##m##_10),"+v"(w##m##_11), \
                    "+v"(w##m##_12),"+v"(w##m##_13),"+v"(w##m##_14),"+v"(w##m##_15)); \
  asm volatile("" : "+v"(w##m##_16),"+v"(w##m##_17),"+v"(w##m##_18),"+v"(w##m##_19), \
                    "+v"(w##m##_20),"+v"(w##m##_21),"+v"(w##m##_22),"+v"(w##m##_23), \
                    "+v"(w##m##_24),"+v"(w##m##_25),"+v"(w##m##_26),"+v"(w##m##_27), \
                    "+v"(w##m##_28),"+v"(w##m##_29),"+v"(w##m##_30),"+v"(w##m##_31));

// 4 independent 8-deep pk_fma chains per gate; tree-combined.
#define DOTG(m) ({ \
  f2v A_ = w##m##_0*hb0;   A_ += w##m##_4*hb4;   A_ += w##m##_8*hb8;    A_ += w##m##_12*hb12; \
      A_ += w##m##_16*hb16; A_ += w##m##_20*hb20; A_ += w##m##_24*hb24; A_ += w##m##_28*hb28; \
  f2v B_ = w##m##_1*hb1;   B_ += w##m##_5*hb5;   B_ += w##m##_9*hb9;    B_ += w##m##_13*hb13; \
      B_ += w##m##_17*hb17; B_ += w##m##_21*hb21; B_ += w##m##_25*hb25; B_ += w##m##_29*hb29; \
  f2v C_ = w##m##_2*hb2;   C_ += w##m##_6*hb6;   C_ += w##m##_10*hb10;  C_ += w##m##_14*hb14; \
      C_ += w##m##_18*hb18; C_ += w##m##_22*hb22; C_ += w##m##_26*hb26; C_ += w##m##_30*hb30; \
  f2v D_ = w##m##_3*hb3;   D_ += w##m##_7*hb7;   D_ += w##m##_11*hb11;  D_ += w##m##_15*hb15; \
      D_ += w##m##_19*hb19; D_ += w##m##_23*hb23; D_ += w##m##_27*hb27; D_ += w##m##_31*hb31; \
  f2v S_ = (A_+B_)+(C_+D_); S_[0]+S_[1]; })

__global__ __attribute__((amdgpu_flat_work_group_size(64,64), amdgpu_waves_per_eu(1,1)))
void lstm_k(
    const float* __restrict__ xproj, const float* __restrict__ Whh,
    const float* __restrict__ W1, const float* __restrict__ b1,
    const float* __restrict__ W2, const float* __restrict__ b2,
    float* __restrict__ out)
{
  const int l = threadIdx.x & 63;
  __shared__ __align__(16) float s_h[64];
  __shared__ float s_y[32];

  WDECL32(0) WDECL32(1) WDECL32(2) WDECL32(3)

  float c=0.f;
  float xp0=xproj[l], xp1=xproj[64+l], xp2=xproj[128+l], xp3=xproj[192+l];
  s_h[l]=0.f;
  __syncthreads();   // once, before the loop (init visibility across the wave)

  for(int t=0;t<1024;t++){
    f2v hb0,hb1,hb2,hb3,hb4,hb5,hb6,hb7,hb8,hb9,hb10,hb11,hb12,hb13,hb14,hb15,
        hb16,hb17,hb18,hb19,hb20,hb21,hb22,hb23,hb24,hb25,hb26,hb27,hb28,hb29,hb30,hb31;
    { float4 v_;
      v_=*(const float4*)(s_h+ 0); hb0 =(f2v){v_.x,v_.y}; hb1 =(f2v){v_.z,v_.w};
      v_=*(const float4*)(s_h+ 4); hb2 =(f2v){v_.x,v_.y}; hb3 =(f2v){v_.z,v_.w};
      v_=*(const float4*)(s_h+ 8); hb4 =(f2v){v_.x,v_.y}; hb5 =(f2v){v_.z,v_.w};
      v_=*(const float4*)(s_h+12); hb6 =(f2v){v_.x,v_.y}; hb7 =(f2v){v_.z,v_.w};
      v_=*(const float4*)(s_h+16); hb8 =(f2v){v_.x,v_.y}; hb9 =(f2v){v_.z,v_.w};
      v_=*(const float4*)(s_h+20); hb10=(f2v){v_.x,v_.y}; hb11=(f2v){v_.z,v_.w};
      v_=*(const float4*)(s_h+24); hb12=(f2v){v_.x,v_.y}; hb13=(f2v){v_.z,v_.w};
      v_=*(const float4*)(s_h+28); hb14=(f2v){v_.x,v_.y}; hb15=(f2v){v_.z,v_.w};
      v_=*(const float4*)(s_h+32); hb16=(f2v){v_.x,v_.y}; hb17=(f2v){v_.z,v_.w};
      v_=*(const float4*)(s_h+36); hb18=(f2v){v_.x,v_.y}; hb19=(f2v){v_.z,v_.w};
      v_=*(const float4*)(s_h+40); hb20=(f2v){v_.x,v_.y}; hb21=(f2v){v_.z,v_.w};
      v_=*(const float4*)(s_h+44); hb22=(f2v){v_.x,v_.y}; hb23=(f2v){v_.z,v_.w};
      v_=*(const float4*)(s_h+48); hb24=(f2v){v_.x,v_.y}; hb25=(f2v){v_.z,v_.w};
      v_=*(const float4*)(s_h+52); hb26=(f2v){v_.x,v_.y}; hb27=(f2v){v_.z,v_.w};
      v_=*(const float4*)(s_h+56); hb28=(f2v){v_.x,v_.y}; hb29=(f2v){v_.z,v_.w};
      v_=*(const float4*)(s_h+60); hb30=(f2v){v_.x,v_.y}; hb31=(f2v){v_.z,v_.w}; }
    float xn0=0.f,xn1=0.f,xn2=0.f,xn3=0.f;
    if(t<1023){
      const float* xpp = xproj + (size_t)(t+1)*256;
      xn0=xpp[l]; xn1=xpp[64+l]; xn2=xpp[128+l]; xn3=xpp[192+l];
    }
    const float d0=DOTG(0), d1=DOTG(1), d2=DOTG(2), d3=DOTG(3);
    const float gi=d0+xp0, gf=d1+xp1, gg=d2+xp2, go=d3+xp3;
    c = sig_(gf)*c + sig_(gi)*tanhf_(gg);
    const float hn = sig_(go)*tanhf_(c);
    s_h[l]=hn;                  // wave-lockstep: all reads above already issued
    xp0=xn0; xp1=xn1; xp2=xn2; xp3=xn3;
  }
  // MLP head: relu(h@W1+b1)@W2+b2
  if(l<32){
    float a=b1[l];
    #pragma unroll 8
    for(int k=0;k<64;k++) a += s_h[k]*W1[k*32+l];
    s_y[l]=fmaxf(a,0.f);
  }
  if(l==0){
    float a=b2[0];
    #pragma unroll
    for(int j=0;j<32;j++) a += s_y[j]*W2[j];
    out[0]=a;
  }
}

extern "C" void kernel_launch(void* const* d_in, const int* in_sizes, int n_in,
                              void* d_out, int out_size, void* d_ws, size_t ws_size,
                              hipStream_t stream) {
  (void)in_sizes; (void)n_in; (void)out_size; (void)ws_size;
  const float* x    = (const float*)d_in[0];
  const int*   ei   = (const int*)d_in[1];
  const float* ea   = (const float*)d_in[2];
  const float* Wl1  = (const float*)d_in[4];
  const float* bl1  = (const float*)d_in[5];
  const float* Wr1  = (const float*)d_in[6];
  const float* br1  = (const float*)d_in[7];
  const float* We1  = (const float*)d_in[8];
  const float* att1 = (const float*)d_in[9];
  const float* bias1= (const float*)d_in[10];
  const float* Wl2  = (const float*)d_in[11];
  const float* bl2  = (const float*)d_in[12];
  const float* Wr2  = (const float*)d_in[13];
  const float* br2  = (const float*)d_in[14];
  const float* We2  = (const float*)d_in[15];
  const float* att2 = (const float*)d_in[16];
  const float* bias2= (const float*)d_in[17];
  const float* Wih  = (const float*)d_in[18];
  const float* Whh  = (const float*)d_in[19];
  const float* bih  = (const float*)d_in[20];
  const float* bhh  = (const float*)d_in[21];
  const float* W1   = (const float*)d_in[22];
  const float* b1   = (const float*)d_in[23];
  const float* W2   = (const float*)d_in[24];
  const float* b2   = (const float*)d_in[25];

  float* h1w = (float*)d_ws;                                  // 65536*192*4 = 50331648 B
  float* xpw = (float*)((char*)d_ws + (size_t)50331648);      // 1024*256*4  = 1048576 B
  float* outp = (float*)d_out;

  gat1_k<<<dim3(SGR), dim3(512), 0, stream>>>(x, ei, ea, Wl1, bl1, Wr1, br1, We1, att1, bias1, h1w);
  gat2_k<<<dim3(SGR), dim3(512), 0, stream>>>(h1w, ei, ea, Wl2, bl2, Wr2, br2, We2, att2, bias2,
                                              Wih, bih, bhh, xpw);
  lstm_k<<<dim3(1), dim3(64), 0, stream>>>(xpw, Whh, W1, b1, W2, b2, outp);
}

// Round 17
// 667.906 us; speedup vs baseline: 1.4852x; 1.4852x over previous
//
#include <hip/hip_runtime.h>

#define ETOT 524288
#define SGR  1024
#define NPG  64
#define EPG  512
#define NFD  32
#define EFD  16
#define HCD  64

typedef float f2v __attribute__((ext_vector_type(2)));

__device__ __forceinline__ float elu_(float x){ return x>0.f ? x : (__expf(x)-1.f); }
__device__ __forceinline__ float sig_(float x){ return 1.f/(1.f+__expf(-x)); }
__device__ __forceinline__ float tanhf_(float x){ float e=__expf(2.f*x); return 1.f-2.f/(e+1.f); }
__device__ __forceinline__ float lrelu_(float x){ return x>0.f ? x : 0.2f*x; }

template<int C>
__device__ __forceinline__ float dppf(float v){
  return __int_as_float(__builtin_amdgcn_update_dpp(0, __float_as_int(v), C, 0xF, 0xF, true));
}
__device__ __forceinline__ float quad_add(float v){
  v += dppf<0xB1>(v);
  return v + dppf<0x4E>(v);
}

// Deterministic CSR build + per-dst mean edge_attr. Fully parallel; bin order = serial scan.
__device__ void build_csr_la(int tid, int g, const int* ei, const float* ea,
                             int* s_edge, int* s_entry, int* s_off, int* s_deg,
                             int* s_cnt, float* s_la)
{
  const int base = g*NPG;
  const int* srcp = ei + (size_t)g*EPG;
  const int* dstp = ei + (size_t)ETOT + (size_t)g*EPG;
  s_edge[tid] = (srcp[tid]-base) | ((dstp[tid]-base)<<6);
  __syncthreads();
  { const int d=tid>>3, s=tid&7, b0=s*64;
    int c=0;
    #pragma unroll 8
    for(int i=0;i<64;i++) c += (((s_edge[b0+i]>>6)&63)==d);
    s_cnt[(d<<3)|s]=c; }
  __syncthreads();
  if(tid<64){ int a=0;
    #pragma unroll
    for(int s=0;s<8;s++) a+=s_cnt[(tid<<3)|s];
    s_deg[tid]=a; }
  __syncthreads();
  if(tid==0){ int a=0;
    for(int i=0;i<64;i++){ s_off[i]=a; a+=s_deg[i]; }
    s_off[64]=a; }
  __syncthreads();
  { const int d=tid>>3, s=tid&7, b0=s*64;
    int pos=s_off[d];
    for(int s2=0;s2<s;s2++) pos += s_cnt[(d<<3)|s2];
    for(int i=0;i<64;i++){ int en=s_edge[b0+i];
      if(((en>>6)&63)==d) s_entry[pos++] = (en&63) | (d<<6) | ((b0+i)<<12); } }
  __syncthreads();
  if(tid<256){ int n=tid>>2, f0=(tid&3)*4;
    float a0=0,a1=0,a2=0,a3=0;
    const int b=s_off[n], en=s_off[n+1];
    for(int p=b;p<en;p++){ int eid=s_entry[p]>>12;
      const float4 v = *(const float4*)(ea + ((size_t)g*EPG+(size_t)eid)*EFD + f0);
      a0+=v.x; a1+=v.y; a2+=v.z; a3+=v.w; }
    float inv = 1.f/fmaxf((float)(en-b),1.f);
    float4 r; r.x=a0*inv; r.y=a1*inv; r.z=a2*inv; r.w=a3*inv;
    *(float4*)(s_la + n*EFD + f0) = r; }
  __syncthreads();
}

// scores (576 = 512 edges + 64 self loops) + per-dst softmax; alpha left in s_sc.
__device__ void scores_softmax(int tid, int g, const float* ea,
   const int* s_entry, const int* s_off, const float* s_la,
   const float* s_We, const float* s_att, const float* s_xl, const float* s_xr,
   float* s_sc)
{
  for(int p=tid;p<576;p+=512){
    int src,dst; float eav[16];
    if(p<EPG){
      int en=s_entry[p]; src=en&63; dst=(en>>6)&63; int eid=en>>12;
      const float* epp = ea + ((size_t)g*EPG + (size_t)eid)*EFD;
      float4 v0=*(const float4*)(epp),   v1=*(const float4*)(epp+4);
      float4 v2=*(const float4*)(epp+8), v3=*(const float4*)(epp+12);
      eav[0]=v0.x;eav[1]=v0.y;eav[2]=v0.z;eav[3]=v0.w;
      eav[4]=v1.x;eav[5]=v1.y;eav[6]=v1.z;eav[7]=v1.w;
      eav[8]=v2.x;eav[9]=v2.y;eav[10]=v2.z;eav[11]=v2.w;
      eav[12]=v3.x;eav[13]=v3.y;eav[14]=v3.z;eav[15]=v3.w;
    } else {
      int n=p-EPG; src=n; dst=n;
      const float* epp = s_la + n*EFD;
      float4 v0=*(const float4*)(epp),   v1=*(const float4*)(epp+4);
      float4 v2=*(const float4*)(epp+8), v3=*(const float4*)(epp+12);
      eav[0]=v0.x;eav[1]=v0.y;eav[2]=v0.z;eav[3]=v0.w;
      eav[4]=v1.x;eav[5]=v1.y;eav[6]=v1.z;eav[7]=v1.w;
      eav[8]=v2.x;eav[9]=v2.y;eav[10]=v2.z;eav[11]=v2.w;
      eav[12]=v3.x;eav[13]=v3.y;eav[14]=v3.z;eav[15]=v3.w;
    }
    float score=0.f;
    #pragma unroll 4
    for(int cq=0;cq<16;cq++){
      float e0=0.f,e1=0.f,e2=0.f,e3=0.f;
      #pragma unroll
      for(int f=0;f<16;f++){
        const float4 wv=*(const float4*)(s_We + f*64 + cq*4);
        e0+=eav[f]*wv.x; e1+=eav[f]*wv.y; e2+=eav[f]*wv.z; e3+=eav[f]*wv.w;
      }
      const float4 xlv=*(const float4*)(s_xl + src*64 + ((cq^(src&15))<<2));
      const float4 xrv=*(const float4*)(s_xr + dst*64 + ((cq^(dst&15))<<2));
      const float4 av =*(const float4*)(s_att + cq*4);
      float m0=lrelu_(xlv.x+xrv.x+e0), m1=lrelu_(xlv.y+xrv.y+e1);
      float m2=lrelu_(xlv.z+xrv.z+e2), m3=lrelu_(xlv.w+xrv.w+e3);
      score += m0*av.x+m1*av.y+m2*av.z+m3*av.w;
    }
    s_sc[p]=score;
  }
  __syncthreads();
  { const int d=tid>>3, s=tid&7;
    const int b=s_off[d], e=s_off[d+1];
    float mx=-1e30f;
    for(int p=b+s;p<e;p+=8) mx=fmaxf(mx,s_sc[p]);
    if(s==0) mx=fmaxf(mx,s_sc[EPG+d]);
    mx=fmaxf(mx,dppf<0xB1>(mx));
    mx=fmaxf(mx,dppf<0x4E>(mx));
    mx=fmaxf(mx,dppf<0x141>(mx));   // row_half_mirror: completes 8-lane reduce
    float den=0.f;
    for(int p=b+s;p<e;p+=8){ float w=__expf(s_sc[p]-mx); s_sc[p]=w; den+=w; }
    float selfv=0.f;
    if(s==0){ selfv=__expf(s_sc[EPG+d]-mx); den+=selfv; }
    den+=dppf<0xB1>(den);
    den+=dppf<0x4E>(den);
    den+=dppf<0x141>(den);
    const float inv=1.f/(den+1e-16f);
    for(int p=b+s;p<e;p+=8) s_sc[p]*=inv;
    if(s==0) s_sc[EPG+d]=selfv*inv;
  }
  __syncthreads();
}

__global__ __launch_bounds__(512,4) void gat1_k(
    const float* __restrict__ x, const int* __restrict__ ei,
    const float* __restrict__ ea, const float* __restrict__ Wl,
    const float* __restrict__ bl, const float* __restrict__ Wr,
    const float* __restrict__ br, const float* __restrict__ We,
    const float* __restrict__ att, const float* __restrict__ bias,
    float* __restrict__ h1)
{
  const int g = blockIdx.x, tid = threadIdx.x;
  const int base = g*NPG;

  __shared__ __align__(16) float s_x[NPG*36];
  __shared__ __align__(16) float s_xl[NPG*64];
  __shared__ __align__(16) float s_xr[NPG*64];
  __shared__ __align__(16) float s_W[2*32*64];
  __shared__ __align__(16) float s_We[16*64];
  __shared__ __align__(16) float s_att[64];
  __shared__ __align__(16) float s_la[NPG*EFD];
  __shared__ float s_sc[576];
  __shared__ int   s_edge[EPG];
  __shared__ int   s_entry[EPG];
  __shared__ int   s_cnt[512];
  __shared__ int   s_off[65];
  __shared__ int   s_deg[64];

  { int n=tid>>3, kq=tid&7;
    float4 v = *(const float4*)(x + (size_t)(base+n)*NFD + kq*4);
    *(float4*)(s_x + n*36 + kq*4) = v; }

  build_csr_la(tid, g, ei, ea, s_edge, s_entry, s_off, s_deg, s_cnt, s_la);

  for(int h=0;h<3;h++){
    { int k=tid>>4, c0=(tid&15)*4;
      *(float4*)(s_W + k*64 + c0)        = *(const float4*)(Wl + (size_t)k*192 + h*64 + c0);
      *(float4*)(s_W + 2048 + k*64 + c0) = *(const float4*)(Wr + (size_t)k*192 + h*64 + c0); }
    if(tid<256){ int f=tid>>4, c0=(tid&15)*4;
      *(float4*)(s_We + f*64 + c0) = *(const float4*)(We + (size_t)f*192 + h*64 + c0); }
    if(tid<16) *(float4*)(s_att + tid*4) = *(const float4*)(att + h*64 + tid*4);
    __syncthreads();

    { const int cg=tid&15, ng=tid>>4, n0=ng*2, c0=cg*4;
      const float4 blv=*(const float4*)(bl + h*64 + c0);
      const float4 brv=*(const float4*)(br + h*64 + c0);
      float accl[2][4]={{blv.x,blv.y,blv.z,blv.w},{blv.x,blv.y,blv.z,blv.w}};
      float accr[2][4]={{brv.x,brv.y,brv.z,brv.w},{brv.x,brv.y,brv.z,brv.w}};
      #pragma unroll
      for(int kq=0;kq<8;kq++){
        float xs0[4], xs1[4];
        { float4 v=*(const float4*)(s_x + n0*36 + kq*4);     xs0[0]=v.x;xs0[1]=v.y;xs0[2]=v.z;xs0[3]=v.w; }
        { float4 v=*(const float4*)(s_x + (n0+1)*36 + kq*4); xs1[0]=v.x;xs1[1]=v.y;xs1[2]=v.z;xs1[3]=v.w; }
        #pragma unroll
        for(int f=0;f<4;f++){
          const float4 wl=*(const float4*)(s_W + (kq*4+f)*64 + c0);
          const float4 wr=*(const float4*)(s_W + 2048 + (kq*4+f)*64 + c0);
          accl[0][0]+=xs0[f]*wl.x; accl[0][1]+=xs0[f]*wl.y; accl[0][2]+=xs0[f]*wl.z; accl[0][3]+=xs0[f]*wl.w;
          accl[1][0]+=xs1[f]*wl.x; accl[1][1]+=xs1[f]*wl.y; accl[1][2]+=xs1[f]*wl.z; accl[1][3]+=xs1[f]*wl.w;
          accr[0][0]+=xs0[f]*wr.x; accr[0][1]+=xs0[f]*wr.y; accr[0][2]+=xs0[f]*wr.z; accr[0][3]+=xs0[f]*wr.w;
          accr[1][0]+=xs1[f]*wr.x; accr[1][1]+=xs1[f]*wr.y; accr[1][2]+=xs1[f]*wr.z; accr[1][3]+=xs1[f]*wr.w;
        }
      }
      #pragma unroll
      for(int i=0;i<2;i++){
        const int n=n0+i, sq=((cg^(n&15))<<2);
        float4 vl; vl.x=accl[i][0]; vl.y=accl[i][1]; vl.z=accl[i][2]; vl.w=accl[i][3];
        float4 vr; vr.x=accr[i][0]; vr.y=accr[i][1]; vr.z=accr[i][2]; vr.w=accr[i][3];
        *(float4*)(s_xl + n*64 + sq)=vl;
        *(float4*)(s_xr + n*64 + sq)=vr;
      }
    }
    __syncthreads();

    scores_softmax(tid, g, ea, s_entry, s_off, s_la, s_We, s_att, s_xl, s_xr, s_sc);

    { const int n=tid>>3, c0a=(tid&7)*8;
      float acc[8]={0.f,0.f,0.f,0.f,0.f,0.f,0.f,0.f};
      const int b=s_off[n], e=s_off[n+1];
      for(int p=b;p<e;p++){
        const int en=s_entry[p], src=en&63;
        const float a=s_sc[p];
        #pragma unroll
        for(int qq=0;qq<2;qq++){
          const int cq=(c0a>>2)+qq;
          const float4 xv=*(const float4*)(s_xl + src*64 + ((cq^(src&15))<<2));
          acc[qq*4+0]+=a*xv.x; acc[qq*4+1]+=a*xv.y; acc[qq*4+2]+=a*xv.z; acc[qq*4+3]+=a*xv.w;
        }
      }
      { const float a=s_sc[EPG+n];
        #pragma unroll
        for(int qq=0;qq<2;qq++){
          const int cq=(c0a>>2)+qq;
          const float4 xv=*(const float4*)(s_xl + n*64 + ((cq^(n&15))<<2));
          acc[qq*4+0]+=a*xv.x; acc[qq*4+1]+=a*xv.y; acc[qq*4+2]+=a*xv.z; acc[qq*4+3]+=a*xv.w;
        } }
      float* op = h1 + (size_t)(base+n)*192 + h*64 + c0a;
      #pragma unroll
      for(int qq=0;qq<2;qq++){
        const float4 bv=*(const float4*)(bias + h*64 + c0a + qq*4);
        float4 r; r.x=elu_(acc[qq*4+0]+bv.x); r.y=elu_(acc[qq*4+1]+bv.y);
                  r.z=elu_(acc[qq*4+2]+bv.z); r.w=elu_(acc[qq*4+3]+bv.w);
        *(float4*)(op + qq*4)=r;
      }
    }
    __syncthreads();
  }
}

__global__ __launch_bounds__(512,4) void gat2_k(
    const float* __restrict__ h1, const int* __restrict__ ei,
    const float* __restrict__ ea, const float* __restrict__ Wl,
    const float* __restrict__ bl, const float* __restrict__ Wr,
    const float* __restrict__ br, const float* __restrict__ We,
    const float* __restrict__ att, const float* __restrict__ bias,
    const float* __restrict__ Wih, const float* __restrict__ bih,
    const float* __restrict__ bhh, float* __restrict__ xproj)
{
  const int g = blockIdx.x, tid = threadIdx.x;
  const int base = g*NPG;

  __shared__ __align__(16) float s_hx[NPG*36];
  __shared__ __align__(16) float s_xl[NPG*64];
  __shared__ __align__(16) float s_xr[NPG*64];
  __shared__ __align__(16) float s_W[2*32*64];
  __shared__ __align__(16) float s_We[16*64];
  __shared__ __align__(16) float s_att[64];
  __shared__ __align__(16) float s_la[NPG*EFD];
  __shared__ float s_sc[576];
  __shared__ float s_pool[64];
  __shared__ int   s_edge[EPG];
  __shared__ int   s_entry[EPG];
  __shared__ int   s_cnt[512];
  __shared__ int   s_off[65];
  __shared__ int   s_deg[64];
  float* s_out = s_W;

  build_csr_la(tid, g, ei, ea, s_edge, s_entry, s_off, s_deg, s_cnt, s_la);

  const int cg=tid&15, ng=tid>>4, n0=ng*2, gc0=cg*4;
  float accl[2][4], accr[2][4];
  { const float4 blv=*(const float4*)(bl + gc0);
    const float4 brv=*(const float4*)(br + gc0);
    #pragma unroll
    for(int i=0;i<2;i++){
      accl[i][0]=blv.x; accl[i][1]=blv.y; accl[i][2]=blv.z; accl[i][3]=blv.w;
      accr[i][0]=brv.x; accr[i][1]=brv.y; accr[i][2]=brv.z; accr[i][3]=brv.w; } }
  for(int kc=0;kc<6;kc++){
    { int n=tid>>3, kq=tid&7;
      *(float4*)(s_hx + n*36 + kq*4) = *(const float4*)(h1 + (size_t)(base+n)*192 + kc*32 + kq*4); }
    { int k=tid>>4, cc=(tid&15)*4;
      *(float4*)(s_W + k*64 + cc)        = *(const float4*)(Wl + (size_t)(kc*32+k)*64 + cc);
      *(float4*)(s_W + 2048 + k*64 + cc) = *(const float4*)(Wr + (size_t)(kc*32+k)*64 + cc); }
    __syncthreads();
    #pragma unroll
    for(int kq=0;kq<8;kq++){
      float xs0[4], xs1[4];
      { float4 v=*(const float4*)(s_hx + n0*36 + kq*4);     xs0[0]=v.x;xs0[1]=v.y;xs0[2]=v.z;xs0[3]=v.w; }
      { float4 v=*(const float4*)(s_hx + (n0+1)*36 + kq*4); xs1[0]=v.x;xs1[1]=v.y;xs1[2]=v.z;xs1[3]=v.w; }
      #pragma unroll
      for(int f=0;f<4;f++){
        const float4 wl=*(const float4*)(s_W + (kq*4+f)*64 + gc0);
        const float4 wr=*(const float4*)(s_W + 2048 + (kq*4+f)*64 + gc0);
        accl[0][0]+=xs0[f]*wl.x; accl[0][1]+=xs0[f]*wl.y; accl[0][2]+=xs0[f]*wl.z; accl[0][3]+=xs0[f]*wl.w;
        accl[1][0]+=xs1[f]*wl.x; accl[1][1]+=xs1[f]*wl.y; accl[1][2]+=xs1[f]*wl.z; accl[1][3]+=xs1[f]*wl.w;
        accr[0][0]+=xs0[f]*wr.x; accr[0][1]+=xs0[f]*wr.y; accr[0][2]+=xs0[f]*wr.z; accr[0][3]+=xs0[f]*wr.w;
        accr[1][0]+=xs1[f]*wr.x; accr[1][1]+=xs1[f]*wr.y; accr[1][2]+=xs1[f]*wr.z; accr[1][3]+=xs1[f]*wr.w;
      }
    }
    __syncthreads();
  }
  #pragma unroll
  for(int i=0;i<2;i++){
    const int n=n0+i, sq=((cg^(n&15))<<2);
    float4 vl; vl.x=accl[i][0]; vl.y=accl[i][1]; vl.z=accl[i][2]; vl.w=accl[i][3];
    float4 vr; vr.x=accr[i][0]; vr.y=accr[i][1]; vr.z=accr[i][2]; vr.w=accr[i][3];
    *(float4*)(s_xl + n*64 + sq)=vl;
    *(float4*)(s_xr + n*64 + sq)=vr;
  }
  if(tid<256){ int f=tid>>4, cc=(tid&15)*4;
    *(float4*)(s_We + f*64 + cc) = *(const float4*)(We + (size_t)f*64 + cc); }
  if(tid<16) *(float4*)(s_att + tid*4) = *(const float4*)(att + tid*4);
  __syncthreads();

  scores_softmax(tid, g, ea, s_entry, s_off, s_la, s_We, s_att, s_xl, s_xr, s_sc);

  { const int n=tid>>3, c0a=(tid&7)*8;
    float acc[8]={0.f,0.f,0.f,0.f,0.f,0.f,0.f,0.f};
    const int b=s_off[n], e=s_off[n+1];
    for(int p=b;p<e;p++){
      const int en=s_entry[p], src=en&63;
      const float a=s_sc[p];
      #pragma unroll
      for(int qq=0;qq<2;qq++){
        const int cq=(c0a>>2)+qq;
        const float4 xv=*(const float4*)(s_xl + src*64 + ((cq^(src&15))<<2));
        acc[qq*4+0]+=a*xv.x; acc[qq*4+1]+=a*xv.y; acc[qq*4+2]+=a*xv.z; acc[qq*4+3]+=a*xv.w;
      }
    }
    { const float a=s_sc[EPG+n];
      #pragma unroll
      for(int qq=0;qq<2;qq++){
        const int cq=(c0a>>2)+qq;
        const float4 xv=*(const float4*)(s_xl + n*64 + ((cq^(n&15))<<2));
        acc[qq*4+0]+=a*xv.x; acc[qq*4+1]+=a*xv.y; acc[qq*4+2]+=a*xv.z; acc[qq*4+3]+=a*xv.w;
      } }
    #pragma unroll
    for(int qq=0;qq<2;qq++){
      const float4 bv=*(const float4*)(bias + c0a + qq*4);
      float4 r; r.x=elu_(acc[qq*4+0]+bv.x); r.y=elu_(acc[qq*4+1]+bv.y);
                r.z=elu_(acc[qq*4+2]+bv.z); r.w=elu_(acc[qq*4+3]+bv.w);
      *(float4*)(s_out + n*64 + c0a + qq*4)=r;
    }
  }
  __syncthreads();
  if(tid<64){ float s=0.f;
    #pragma unroll 8
    for(int n2=0;n2<64;n2++) s += s_out[n2*64+tid];
    s_pool[tid]=s*(1.f/64.f); }
  __syncthreads();
  if(tid<256){
    float a=bih[tid]+bhh[tid];
    #pragma unroll
    for(int kq=0;kq<16;kq++){
      const float4 w=*(const float4*)(Wih + (size_t)tid*64 + kq*4);
      a += w.x*s_pool[kq*4+0] + w.y*s_pool[kq*4+1] + w.z*s_pool[kq*4+2] + w.w*s_pool[kq*4+3];
    }
    xproj[(size_t)g*256 + tid]=a;
  }
}

// ---- LSTM (r9-exact): 256 thr, (l,q)=(tid>>2,tid&3); f2v weights resident
// (waves_per_eu(1,1), VGPR=132 verified); depth-4 xproj ring, statically indexed.
__device__ __forceinline__ float dot2_(f2v w0,f2v w1,f2v w2,f2v w3,f2v w4,f2v w5,f2v w6,f2v w7,
                                       f2v h0,f2v h1,f2v h2,f2v h3,f2v h4,f2v h5,f2v h6,f2v h7){
  f2v a = w0*h0; a += w1*h1; a += w2*h2; a += w3*h3;
  f2v b = w4*h4; b += w5*h5; b += w6*h6; b += w7*h7;
  f2v s = a+b; return s[0]+s[1];
}

#define WDECL(m) \
  f2v w##m##_0,w##m##_1,w##m##_2,w##m##_3,w##m##_4,w##m##_5,w##m##_6,w##m##_7; \
  { const float* wp_ = Whh + (size_t)((m)*64+l)*64 + q*16; \
    const float4 a_=*(const float4*)(wp_),   b_=*(const float4*)(wp_+4); \
    const float4 c_=*(const float4*)(wp_+8), d_=*(const float4*)(wp_+12); \
    w##m##_0=(f2v){a_.x,a_.y}; w##m##_1=(f2v){a_.z,a_.w}; \
    w##m##_2=(f2v){b_.x,b_.y}; w##m##_3=(f2v){b_.z,b_.w}; \
    w##m##_4=(f2v){c_.x,c_.y}; w##m##_5=(f2v){c_.z,c_.w}; \
    w##m##_6=(f2v){d_.x,d_.y}; w##m##_7=(f2v){d_.z,d_.w}; } \
  asm volatile("" : "+v"(w##m##_0),"+v"(w##m##_1),"+v"(w##m##_2),"+v"(w##m##_3), \
                    "+v"(w##m##_4),"+v"(w##m##_5),"+v"(w##m##_6),"+v"(w##m##_7));

#define DOTP(m) dot2_(w##m##_0,w##m##_1,w##m##_2,w##m##_3,w##m##_4,w##m##_5,w##m##_6,w##m##_7, \
                      hb0,hb1,hb2,hb3,hb4,hb5,hb6,hb7)

#define XQDECL(k) \
  float xq##k##_0,xq##k##_1,xq##k##_2,xq##k##_3; \
  { const float* xpp_ = xproj + (size_t)(k)*256; \
    xq##k##_0=xpp_[l]; xq##k##_1=xpp_[64+l]; xq##k##_2=xpp_[128+l]; xq##k##_3=xpp_[192+l]; }

#define STEP(k) { \
    f2v hb0,hb1,hb2,hb3,hb4,hb5,hb6,hb7; \
    { const float* hp_ = &s_h[cur][q*16]; \
      const float4 a_=*(const float4*)(hp_),   b_=*(const float4*)(hp_+4); \
      const float4 c_=*(const float4*)(hp_+8), d_=*(const float4*)(hp_+12); \
      hb0=(f2v){a_.x,a_.y}; hb1=(f2v){a_.z,a_.w}; \
      hb2=(f2v){b_.x,b_.y}; hb3=(f2v){b_.z,b_.w}; \
      hb4=(f2v){c_.x,c_.y}; hb5=(f2v){c_.z,c_.w}; \
      hb6=(f2v){d_.x,d_.y}; hb7=(f2v){d_.z,d_.w}; } \
    const float cx0=xq##k##_0, cx1=xq##k##_1, cx2=xq##k##_2, cx3=xq##k##_3; \
    if(tb+(k)+4<1024){ \
      const float* xpp_ = xproj + (size_t)(tb+(k)+4)*256; \
      xq##k##_0=xpp_[l]; xq##k##_1=xpp_[64+l]; xq##k##_2=xpp_[128+l]; xq##k##_3=xpp_[192+l]; \
    } \
    float a0=quad_add(DOTP(0)); \
    float a1=quad_add(DOTP(1)); \
    float a2=quad_add(DOTP(2)); \
    float a3=quad_add(DOTP(3)); \
    const float gi=a0+cx0, gf=a1+cx1, gg=a2+cx2, go=a3+cx3; \
    c = sig_(gf)*c + sig_(gi)*tanhf_(gg); \
    const float hn = sig_(go)*tanhf_(c); \
    if(q==0) s_h[cur^1][l]=hn; \
    cur^=1; \
    __syncthreads(); \
  }

__global__ __attribute__((amdgpu_flat_work_group_size(256,256), amdgpu_waves_per_eu(1,1)))
void lstm_k(
    const float* __restrict__ xproj, const float* __restrict__ Whh,
    const float* __restrict__ W1, const float* __restrict__ b1,
    const float* __restrict__ W2, const float* __restrict__ b2,
    float* __restrict__ out)
{
  const int tid=threadIdx.x, l=tid>>2, q=tid&3;
  __shared__ __align__(16) float s_h[2][64];
  __shared__ float s_y[32];

  WDECL(0) WDECL(1) WDECL(2) WDECL(3)
  XQDECL(0) XQDECL(1) XQDECL(2) XQDECL(3)

  float c=0.f;
  if(tid<64){ s_h[0][tid]=0.f; s_h[1][tid]=0.f; }
  __syncthreads();
  int cur=0;
  for(int tb=0;tb<1024;tb+=4){
    STEP(0) STEP(1) STEP(2) STEP(3)
  }
  if(tid<32){
    float a=b1[tid];
    #pragma unroll 8
    for(int k=0;k<64;k++) a += s_h[cur][k]*W1[k*32+tid];
    s_y[tid]=fmaxf(a,0.f);
  }
  __syncthreads();
  if(tid==0){
    float a=b2[0];
    #pragma unroll
    for(int j=0;j<32;j++) a += s_y[j]*W2[j];
    out[0]=a;
  }
}

extern "C" void kernel_launch(void* const* d_in, const int* in_sizes, int n_in,
                              void* d_out, int out_size, void* d_ws, size_t ws_size,
                              hipStream_t stream) {
  (void)in_sizes; (void)n_in; (void)out_size; (void)ws_size;
  const float* x    = (const float*)d_in[0];
  const int*   ei   = (const int*)d_in[1];
  const float* ea   = (const float*)d_in[2];
  const float* Wl1  = (const float*)d_in[4];
  const float* bl1  = (const float*)d_in[5];
  const float* Wr1  = (const float*)d_in[6];
  const float* br1  = (const float*)d_in[7];
  const float* We1  = (const float*)d_in[8];
  const float* att1 = (const float*)d_in[9];
  const float* bias1= (const float*)d_in[10];
  const float* Wl2  = (const float*)d_in[11];
  const float* bl2  = (const float*)d_in[12];
  const float* Wr2  = (const float*)d_in[13];
  const float* br2  = (const float*)d_in[14];
  const float* We2  = (const float*)d_in[15];
  const float* att2 = (const float*)d_in[16];
  const float* bias2= (const float*)d_in[17];
  const float* Wih  = (const float*)d_in[18];
  const float* Whh  = (const float*)d_in[19];
  const float* bih  = (const float*)d_in[20];
  const float* bhh  = (const float*)d_in[21];
  const float* W1   = (const float*)d_in[22];
  const float* b1   = (const float*)d_in[23];
  const float* W2   = (const float*)d_in[24];
  const float* b2   = (const float*)d_in[25];

  float* h1w = (float*)d_ws;                                  // 65536*192*4 = 50331648 B
  float* xpw = (float*)((char*)d_ws + (size_t)50331648);      // 1024*256*4  = 1048576 B
  float* outp = (float*)d_out;

  gat1_k<<<dim3(SGR), dim3(512), 0, stream>>>(x, ei, ea, Wl1, bl1, Wr1, br1, We1, att1, bias1, h1w);
  gat2_k<<<dim3(SGR), dim3(512), 0, stream>>>(h1w, ei, ea, Wl2, bl2, Wr2, br2, We2, att2, bias2,
                                              Wih, bih, bhh, xpw);
  lstm_k<<<dim3(1), dim3(256), 0, stream>>>(xpw, Whh, W1, b1, W2, b2, outp);
}